// Round 10
// baseline (587.676 us; speedup 1.0000x reference)
//
#include <hip/hip_runtime.h>
#include <hip/hip_fp16.h>

// HeteroGraphSage: 2-layer SAGEConv(mean) + PReLU + input-skip.
// N=100000, IN=D=64, E=1600000, fp32 in/out. Mean degree 16.
// Gather from fp16 table (one 128B line per edge); octet layout: 8 edges
// per 1KB wave-load (o=lane>>3 edge, g=lane&7 -> 16B chunk).
// R10: (a) __launch_bounds__(512,3) -> ~170 VGPR so 8 h2x4 loads stay in
// flight (R9's 48 VGPR forced load serialization); (b) src select via one
// dynamic __shfl (ds_bpermute) instead of 8 readlane + 7 cndmask; (c) wave-
// uniform per-node degree skip kills the ~2x sentinel-slot inflation from
// the shared max-degree loop bound.

#define BLOCK 512

struct alignas(16) h2x4 { __half2 a, b, c, d; };

__global__ __launch_bounds__(256) void hist_kernel(
    const int* __restrict__ dst, int* __restrict__ deg, int E)
{
    int i = blockIdx.x * blockDim.x + threadIdx.x;
    int stride = gridDim.x * blockDim.x;
    for (int e = i; e < E; e += stride) atomicAdd(&deg[dst[e]], 1);
}

__global__ __launch_bounds__(256) void bsum_kernel(
    const int* __restrict__ deg, int* __restrict__ bsum, int n)
{
    __shared__ int sh[256];
    int i = blockIdx.x * 256 + threadIdx.x;
    sh[threadIdx.x] = (i < n) ? deg[i] : 0;
    __syncthreads();
    for (int s = 128; s > 0; s >>= 1) {
        if (threadIdx.x < s) sh[threadIdx.x] += sh[threadIdx.x + s];
        __syncthreads();
    }
    if (threadIdx.x == 0) bsum[blockIdx.x] = sh[0];
}

__global__ __launch_bounds__(512) void scanb_kernel(
    const int* __restrict__ bsum, int* __restrict__ bsumX, int nb)
{
    __shared__ int sh[512];
    int tid = threadIdx.x;
    int v = (tid < nb) ? bsum[tid] : 0;
    sh[tid] = v;
    __syncthreads();
    for (int off = 1; off < 512; off <<= 1) {
        int t = (tid >= off) ? sh[tid - off] : 0;
        __syncthreads();
        sh[tid] += t;
        __syncthreads();
    }
    bsumX[tid] = sh[tid] - v;   // exclusive
}

__global__ __launch_bounds__(256) void rowstart_kernel(
    const int* __restrict__ deg, const int* __restrict__ bsumX,
    int* __restrict__ rowStart, int* __restrict__ cursor, int n)
{
    __shared__ int sh[256];
    int tid = threadIdx.x;
    int i = blockIdx.x * 256 + tid;
    int v = (i < n) ? deg[i] : 0;
    sh[tid] = v;
    __syncthreads();
    for (int off = 1; off < 256; off <<= 1) {
        int t = (tid >= off) ? sh[tid - off] : 0;
        __syncthreads();
        sh[tid] += t;
        __syncthreads();
    }
    if (i < n) {
        int rs = sh[tid] - v + bsumX[blockIdx.x];
        rowStart[i] = rs;
        cursor[i]   = rs;
    }
}

__global__ __launch_bounds__(256) void fill_kernel(
    const int* __restrict__ src, const int* __restrict__ dst,
    int* __restrict__ cursor, unsigned int* __restrict__ esort, int E)
{
    int i = blockIdx.x * blockDim.x + threadIdx.x;
    int stride = gridDim.x * blockDim.x;
    for (int e = i; e < E; e += stride) {
        int d = dst[e];
        int pos = atomicAdd(&cursor[d], 1);
        esort[pos] = (unsigned int)src[e];
    }
}

// fp32 -> fp16 table (m = count of float2 pairs)
__global__ __launch_bounds__(256) void cvt_half_kernel(
    const float2* __restrict__ in, __half2* __restrict__ out, int m)
{
    int i = blockIdx.x * blockDim.x + threadIdx.x;
    int stride = gridDim.x * blockDim.x;
    for (; i < m; i += stride) {
        float2 v = in[i];
        out[i] = __floats2half2_rn(v.x, v.y);
    }
}

static __device__ inline __half2 h2shfl_xor(__half2 v, int mask) {
    union { __half2 h; int i; } u; u.h = v;
    u.i = __shfl_xor(u.i, mask);
    return u.h;
}

// out = PReLU( mean_agg @ wl^T + bl + hin @ wr^T , a ) + x0 @ wskip^T + bskip
// hh: PADDED fp16 table (row n = zeros) used for gather AND the root term.
// x0: fp32 skip input. Writes fp16 (out_h) if non-null, else fp32 (out_f).
__global__ __launch_bounds__(BLOCK, 3) void layer_kernel(
    const int* __restrict__ rowStart, const int* __restrict__ deg,
    const unsigned int* __restrict__ esort,
    const __half* __restrict__ hh, const float* __restrict__ x0,
    const float* __restrict__ wl, const float* __restrict__ bl,
    const float* __restrict__ wr, const float* __restrict__ wskip,
    const float* __restrict__ bskip, const float* __restrict__ aprelu,
    float* __restrict__ out_f, __half* __restrict__ out_h, int n)
{
    // stride 65: dword idx = 65*r + c -> bank (r+c)%32; all patterns 2-way.
    __shared__ float agg_s[64 * 65];
    __shared__ float h_s[64 * 65];
    __shared__ float x_s[64 * 65];

    const int tid  = threadIdx.x;
    const int lane = tid & 63;
    const int wvu  = __builtin_amdgcn_readfirstlane(tid >> 6);  // 0..7
    const int o    = lane >> 3;   // edge octet 0..7
    const int g    = lane & 7;    // 16B chunk of the 128B fp16 row

    const int tileBase = blockIdx.x * 64;
    const int tileEnd  = min(tileBase + 64, n);

    // stage root (fp16 table -> fp32 LDS) and skip (fp32)
    const __half2* hh2 = (const __half2*)hh;
    for (int i = tid; i < 64 * 32; i += BLOCK) {
        const int nl = i >> 5, c2 = i & 31;
        const int node = tileBase + nl;
        float2 hv = make_float2(0.f, 0.f);
        if (node < n) hv = __half22float2(hh2[(size_t)node * 32 + c2]);
        h_s[nl * 65 + 2 * c2]     = hv.x;
        h_s[nl * 65 + 2 * c2 + 1] = hv.y;
    }
    for (int i = tid; i < 64 * 64; i += BLOCK) {
        const int nl = i >> 6, d = i & 63;
        const int node = tileBase + nl;
        x_s[nl * 65 + d] = (node < n) ? x0[(size_t)node * 64 + d] : 0.f;
    }

    // ---- Phase A: wave owns nodes n0..n0+7; 8 edges per 1KB load.
    const int n0 = tileBase + wvu * 8;
    int rs_k[8], dg_k[8];
#pragma unroll
    for (int k = 0; k < 8; k++) {
        const int nd = n0 + k;
        const bool v = nd < tileEnd;
        rs_k[k] = v ? rowStart[nd] : 0;
        dg_k[k] = v ? deg[nd] : 0;
    }

    unsigned int ew[8];
#pragma unroll
    for (int k = 0; k < 8; k++) {
        unsigned int w = (unsigned int)n;            // zero-row sentinel
        if (lane < dg_k[k]) w = esort[rs_k[k] + lane];
        ew[k] = w;
    }

    __half2 acc[8][4];
    const __half2 z2 = __floats2half2_rn(0.f, 0.f);
#pragma unroll
    for (int k = 0; k < 8; k++) {
        acc[k][0] = z2; acc[k][1] = z2; acc[k][2] = z2; acc[k][3] = z2;
    }

    int mx = 0;
#pragma unroll
    for (int k = 0; k < 8; k++) mx = max(mx, min(dg_k[k], 64));

    const h2x4* tab = (const h2x4*)hh;   // row = 8 chunks of 16B
    for (int j = 0; j < mx; j += 8) {
#pragma unroll
        for (int k = 0; k < 8; k++) {
            if (j < dg_k[k]) {                       // wave-uniform skip
                // one ds_bpermute replaces 8 readlane + 7 cndmask
                const int s = __shfl((int)ew[k], j + o);
                const h2x4 v = tab[(size_t)s * 8 + g];   // 1 line per edge
                acc[k][0] = __hadd2(acc[k][0], v.a);
                acc[k][1] = __hadd2(acc[k][1], v.b);
                acc[k][2] = __hadd2(acc[k][2], v.c);
                acc[k][3] = __hadd2(acc[k][3], v.d);
            }
        }
    }

    // rare tail: deg > 64
#pragma unroll
    for (int k = 0; k < 8; k++) {
        if (dg_k[k] > 64) {
            int pos = rs_k[k] + 64, rem = dg_k[k] - 64;
            while (rem > 0) {
                const int cnt = min(64, rem);
                unsigned int w = (unsigned int)n;
                if (lane < cnt) w = esort[pos + lane];
                for (int j = 0; j < cnt; j += 8) {
                    const int s = __shfl((int)w, j + o);
                    const h2x4 v = tab[(size_t)s * 8 + g];
                    acc[k][0] = __hadd2(acc[k][0], v.a);
                    acc[k][1] = __hadd2(acc[k][1], v.b);
                    acc[k][2] = __hadd2(acc[k][2], v.c);
                    acc[k][3] = __hadd2(acc[k][3], v.d);
                }
                pos += cnt; rem -= cnt;
            }
        }
    }

    // flush: reduce across octets (xor 8,16,32); lane (o,g) owns feature 8g+o
#pragma unroll
    for (int k = 0; k < 8; k++) {
        const int nd = n0 + k;
        if (nd < tileEnd) {
            __half2 a0 = acc[k][0], a1 = acc[k][1], a2 = acc[k][2], a3 = acc[k][3];
#pragma unroll
            for (int m = 8; m <= 32; m <<= 1) {
                a0 = __hadd2(a0, h2shfl_xor(a0, m));
                a1 = __hadd2(a1, h2shfl_xor(a1, m));
                a2 = __hadd2(a2, h2shfl_xor(a2, m));
                a3 = __hadd2(a3, h2shfl_xor(a3, m));
            }
            const __half2 sel2 = (o >= 6) ? a3 : (o >= 4) ? a2 : (o >= 2) ? a1 : a0;
            const float hv = (o & 1) ? __high2float(sel2) : __low2float(sel2);
            const float inv = 1.0f / fmaxf((float)dg_k[k], 1.0f);
            agg_s[(nd - tileBase) * 65 + 8 * g + o] = hv * inv;
        }
    }
    __syncthreads();

    // ---- Phase B: dense. lane = node; wave covers dims [wvu*8, wvu*8+8).
    float acc1[8], acc2[8], acc3[8];
#pragma unroll
    for (int dd = 0; dd < 8; dd++) { acc1[dd] = 0.f; acc2[dd] = 0.f; acc3[dd] = 0.f; }

    for (int kc = 0; kc < 8; kc++) {
        float ak[8], hk[8], xk[8];
#pragma unroll
        for (int k = 0; k < 8; k++) {
            ak[k] = agg_s[lane * 65 + kc * 8 + k];
            hk[k] = h_s[lane * 65 + kc * 8 + k];
            xk[k] = x_s[lane * 65 + kc * 8 + k];
        }
#pragma unroll
        for (int dd = 0; dd < 8; dd++) {
            const int d = wvu * 8 + dd;            // wave-uniform -> s_loads
            const float* wlr = wl    + d * 64 + kc * 8;
            const float* wrr = wr    + d * 64 + kc * 8;
            const float* wsr = wskip + d * 64 + kc * 8;
#pragma unroll
            for (int k = 0; k < 8; k++) {
                acc1[dd] += ak[k] * wlr[k];
                acc2[dd] += hk[k] * wrr[k];
                acc3[dd] += xk[k] * wsr[k];
            }
        }
    }
    __syncthreads();   // all waves done reading agg_s before alias-write

    float* out_s = agg_s;
#pragma unroll
    for (int dd = 0; dd < 8; dd++) {
        const int d = wvu * 8 + dd;
        float z = acc1[dd] + acc2[dd] + bl[d];
        z = (z >= 0.f) ? z : aprelu[d] * z;
        out_s[lane * 65 + d] = z + acc3[dd] + bskip[d];
    }
    __syncthreads();

    for (int i = tid; i < 64 * 64; i += BLOCK) {
        const int nl = i >> 6, d = i & 63;
        const int nd = tileBase + nl;
        if (nd < n) {
            const float v = out_s[nl * 65 + d];
            if (out_h) out_h[(size_t)nd * 64 + d] = __float2half(v);
            else       out_f[(size_t)nd * 64 + d] = v;
        }
    }
}

extern "C" void kernel_launch(void* const* d_in, const int* in_sizes, int n_in,
                              void* d_out, int out_size, void* d_ws, size_t ws_size,
                              hipStream_t stream)
{
    const float* x   = (const float*)d_in[0];
    const int*   ei  = (const int*)d_in[1];
    const float* wl0 = (const float*)d_in[2];
    const float* bl0 = (const float*)d_in[3];
    const float* wr0 = (const float*)d_in[4];
    const float* ws0 = (const float*)d_in[5];
    const float* bs0 = (const float*)d_in[6];
    const float* a0  = (const float*)d_in[7];
    const float* wl1 = (const float*)d_in[8];
    const float* bl1 = (const float*)d_in[9];
    const float* wr1 = (const float*)d_in[10];
    const float* ws1 = (const float*)d_in[11];
    const float* bs1 = (const float*)d_in[12];
    const float* a1  = (const float*)d_in[13];

    const int n = in_sizes[0] / 64;
    const int E = in_sizes[1] / 2;
    const int* src = ei;
    const int* dst = ei + E;

    int* deg            = (int*)d_ws;
    int* cursor         = deg + n;
    int* rowStart       = cursor + n;
    int* bsum           = rowStart + n;
    int* bsumX          = bsum + 512;
    unsigned int* esort = (unsigned int*)(bsumX + 512);
    __half* xh          = (__half*)(esort + E);            // (n+1)*64, row n=0
    __half* h1h         = xh + (size_t)(n + 1) * 64;       // (n+1)*64, row n=0

    hipMemsetAsync(deg, 0, (size_t)n * sizeof(int), stream);
    hipMemsetAsync(xh  + (size_t)n * 64, 0, 64 * sizeof(__half), stream);
    hipMemsetAsync(h1h + (size_t)n * 64, 0, 64 * sizeof(__half), stream);

    const int nb = (n + 255) / 256;   // 391 <= 512

    cvt_half_kernel<<<1024, 256, 0, stream>>>(
        (const float2*)x, (__half2*)xh, n * 32);
    hist_kernel<<<2048, 256, 0, stream>>>(dst, deg, E);
    bsum_kernel<<<nb, 256, 0, stream>>>(deg, bsum, n);
    scanb_kernel<<<1, 512, 0, stream>>>(bsum, bsumX, nb);
    rowstart_kernel<<<nb, 256, 0, stream>>>(deg, bsumX, rowStart, cursor, n);
    fill_kernel<<<2048, 256, 0, stream>>>(src, dst, cursor, esort, E);

    const int ntiles = (n + 63) / 64;

    layer_kernel<<<ntiles, BLOCK, 0, stream>>>(rowStart, deg, esort,
        xh, x, wl0, bl0, wr0, ws0, bs0, a0, nullptr, h1h, n);
    layer_kernel<<<ntiles, BLOCK, 0, stream>>>(rowStart, deg, esort,
        h1h, x, wl1, bl1, wr1, ws1, bs1, a1, (float*)d_out, nullptr, n);
}